// Round 5
// baseline (188.380 us; speedup 1.0000x reference)
//
#include <hip/hip_runtime.h>
#include <cstdint>
#include <cstddef>

// Problem constants (from reference: B,T,N = 512,1024,48)
constexpr int Bb = 512;
constexpr int Tt = 1024;
constexpr int Nn = 48;
constexpr int SG = 16;          // sequences per wave (MFMA N dimension here)
constexpr int NG = Bb / SG;     // 32 sequence-groups
constexpr int Cc = 64;          // time-chunks per sequence (grid = 2048 -> 2 waves/SIMD)
constexpr int Lc = Tt / Cc;     // 16 steps per chunk window
constexpr int Wb = 32;          // burn-in steps (R5/R8 validated)

typedef short bf16x8 __attribute__((ext_vector_type(8)));
typedef float f32x4  __attribute__((ext_vector_type(4)));
typedef unsigned int u32x4 __attribute__((ext_vector_type(4)));

__device__ __forceinline__ unsigned int bf16_rne(float x) {
    const unsigned int u = __float_as_uint(x);
    return ((u + 0x7FFFu + ((u >> 16) & 1u)) >> 16);
}
__device__ __forceinline__ unsigned int pack2(float lo, float hi) {
    return bf16_rne(lo) | (bf16_rne(hi) << 16);
}
__device__ __forceinline__ float safe_log(float x) {
    return __logf(fmaxf(x, 1e-30f));   // NaN/inf-proof (fmax discards NaN)
}

// Volatile asm load: the compiler cannot sink/remat/delete it, so the
// prefetch distance we write is the distance the hardware sees.
// SOUNDNESS REQUIREMENT (R4 lesson): the asm outputs must NEVER be spilled --
// the compiler would spill without waiting vmcnt (it assumes asm results are
// synchronous), storing garbage. waves_per_eu(2,2) pins the allocator budget
// at 256 VGPRs so the ~180 live registers fit with zero spills.
#define GLD(dst, p) asm volatile("global_load_dwordx4 %0, %1, off" : "=&v"(dst) : "v"(p))
// Drain to 9 outstanding = 3 batches (of 3 loads) still in flight, i.e. the
// batch 4 steps old is complete. sched_barrier stops the scheduler from
// hoisting the dependent exps above the wait (rule #18).
#define WAITP() do { asm volatile("s_waitcnt vmcnt(9)"); __builtin_amdgcn_sched_barrier(0); } while (0)

// ---------------------------------------------------------------------------
// Operand-swapped recurrence (R3, verified): D[j][m] = sum_i E^T[j][i]*alpha[m][i];
// E fragment = MFMA A operand, alpha = B operand. D: seq m = ln, state j =
// 16nt+4q+r. K-slot->state bijection (same on A and B):
//   kc0: slot (q,d) -> 16*(d>>2)+4q+(d&3)  => B0 = lane's own packed pk words.
//   kc1: slot (q,d) -> 32+8q+d (q<2)       => B1 = 4 bpermute pulls of pk2x.
// Renorm per-lane uniform, division deferred into next step's epv multiply;
// gacc gate (t+1 < len); last active step's log c captured by final rowsum.
// Pot prefetch: volatile-asm dwordx4, distance 4, counted vmcnt(9).
// This round: amdgpu_waves_per_eu(2,2) pins regalloc (no spills -> counted
// vmcnt sound again; R4's absmax=4.0 was unwaited spill of asm outputs).
// ---------------------------------------------------------------------------
__attribute__((amdgpu_waves_per_eu(2, 2)))
__launch_bounds__(64)
__global__ void crf_fused(const float* __restrict__ pot,
                          const int*   __restrict__ ytrue,
                          const int*   __restrict__ lengths,
                          const float* __restrict__ trans,
                          float*       __restrict__ out)
{
    __shared__ float trans_lds[Nn * Nn];

    const int lane = threadIdx.x;
    const int ln   = lane & 15;          // sequence index within group (MFMA N)
    const int q    = lane >> 4;          // quad
    const int gidx = blockIdx.x >> 6;    // sequence group (Cc == 64)
    const int c    = blockIdx.x & 63;    // chunk
    const int s0   = gidx * SG;

    for (int i = lane; i < Nn * Nn; i += 64) trans_lds[i] = trans[i];
    __syncthreads();   // once, outside the loop

    // ---- Gold-path score: sequence b = blockIdx.x>>2, quarter h = blockIdx.x&3.
    {
        const int    b    = blockIdx.x >> 2;
        const int    h    = blockIdx.x & 3;
        const int    lenb = lengths[b];
        const int*   yrow = ytrue + (size_t)b * Tt;
        const float* prow = pot + (size_t)b * Tt * Nn;
        float gold = 0.0f;
#pragma unroll
        for (int k = 0; k < Tt / 256; ++k) {          // 4 iters x 64 lanes = 256 t
            const int   t    = h * (Tt / 4) + lane + 64 * k;
            const int   yt   = yrow[t];
            const int   ytm1 = yrow[(t > 0) ? (t - 1) : 0];
            const float u    = prow[(size_t)t * Nn + yt];
            const float tr   = trans_lds[ytm1 * Nn + yt];
            gold += (t < lenb) ? u : 0.0f;
            gold += (t >= 1 && t < lenb) ? tr : 0.0f;
        }
#pragma unroll
        for (int off = 32; off > 0; off >>= 1) gold += __shfl_xor(gold, off);
        if (lane == 0) atomicAdd(&out[b], -gold);
    }

    const int len_ln = lengths[s0 + ln];         // per-lane sequence length
    int lmax = len_ln;
#pragma unroll
    for (int off = 8; off > 0; off >>= 1) {
        const int o = __shfl_xor(lmax, off);
        lmax = (o > lmax) ? o : lmax;
    }

    const int start = (c == 0) ? 1 : c * Lc;
    if (c > 0 && start >= lmax) return;          // chunk past every row (gold done)
    const int end = ((c + 1) * Lc < lmax) ? (c + 1) * Lc : lmax;

    // A-operand fragments (E^T slices) with the K-slot->state maps above.
    bf16x8 Wf[3][2];
#pragma unroll
    for (int nt = 0; nt < 3; ++nt)
#pragma unroll
        for (int kc = 0; kc < 2; ++kc)
#pragma unroll
            for (int d = 0; d < 8; ++d) {
                int i;
                if (kc == 0) {
                    i = 16 * (d >> 2) + 4 * q + (d & 3);
                } else {
                    i = (q < 2) ? (32 + 8 * q + d) : -1;   // identity order = B1 packing
                }
                const float v = (i >= 0) ? __expf(trans_lds[i * Nn + nt * 16 + ln]) : 0.0f;
                Wf[nt][kc][d] = (short)bf16_rne(v);
            }

    // Cross-lane source lanes for B1 words / c broadcast (precomputed once).
    const int slA = ((2 * q) & 3) * 16 + ln;     // quad 2q   (meaningful for q<2)
    const int slB = slA + 16;                    // quad 2q+1
    const int slC = ln;                          // c broadcast: quad-0 lane ln

    // Per-lane pot row (sequence s0+ln); the lane's 3 float4 groups.
    const float* prow = pot + (size_t)(s0 + ln) * (Tt * Nn);
    const float* pp0 = prow + 0 * 16 + q * 4;
    const float* pp1 = prow + 1 * 16 + q * 4;
    const float* pp2 = prow + 2 * 16 + q * 4;

    int t0 = (c == 0) ? 1 : (start - Wb);
    if (t0 < 1) t0 = 1;                          // c=1,2: exact full recompute

    // ---- Init alpha from pot[t0-1], normalized so alpha[m][0] = 1.
    f32x4 pin0 = *(const f32x4*)(pp0 + (size_t)(t0 - 1) * Nn);
    f32x4 pin1 = *(const f32x4*)(pp1 + (size_t)(t0 - 1) * Nn);
    f32x4 pin2 = *(const f32x4*)(pp2 + (size_t)(t0 - 1) * Nn);
    const float cb0 = __shfl(pin0[0], slC);      // pot[seq ln][state 0]

    float gacc = (c == 0) ? cb0 : 0.0f;          // per-lane (seq = ln)
    f32x4 prev0, prev1, prev2;
#pragma unroll
    for (int r = 0; r < 4; ++r) {
        prev0[r] = __expf(pin0[r] - cb0);
        prev1[r] = __expf(pin1[r] - cb0);
        prev2[r] = __expf(pin2[r] - cb0);
    }

    unsigned int pk00 = pack2(prev0[0], prev0[1]);
    unsigned int pk01 = pack2(prev0[2], prev0[3]);
    unsigned int pk10 = pack2(prev1[0], prev1[1]);
    unsigned int pk11 = pack2(prev1[2], prev1[3]);
    unsigned int pk20 = pack2(prev2[0], prev2[1]);
    unsigned int pk21 = pack2(prev2[2], prev2[3]);
    bf16x8 Bf0 = __builtin_bit_cast(bf16x8, (u32x4){pk00, pk01, pk10, pk11});
    bf16x8 Bf1 = __builtin_bit_cast(bf16x8, (u32x4){
        (unsigned int)__shfl((int)pk20, slA), (unsigned int)__shfl((int)pk21, slA),
        (unsigned int)__shfl((int)pk20, slB), (unsigned int)__shfl((int)pk21, slB)});

    // ---- Named prefetch slots, distance 4, loaded via volatile asm.
    f32x4 P00, P01, P02, P10, P11, P12, P20, P21, P22, P30, P31, P32;
    {
        const size_t ta = (size_t)((t0 + 0 < Tt) ? t0 + 0 : Tt - 1) * Nn;
        const size_t tb = (size_t)((t0 + 1 < Tt) ? t0 + 1 : Tt - 1) * Nn;
        const size_t tc = (size_t)((t0 + 2 < Tt) ? t0 + 2 : Tt - 1) * Nn;
        const size_t td = (size_t)((t0 + 3 < Tt) ? t0 + 3 : Tt - 1) * Nn;
        const float* a;
        a = pp0 + ta; GLD(P00, a);  a = pp1 + ta; GLD(P01, a);  a = pp2 + ta; GLD(P02, a);
        a = pp0 + tb; GLD(P10, a);  a = pp1 + tb; GLD(P11, a);  a = pp2 + tb; GLD(P12, a);
        a = pp0 + tc; GLD(P20, a);  a = pp1 + tc; GLD(P21, a);  a = pp2 + tc; GLD(P22, a);
        a = pp0 + td; GLD(P30, a);  a = pp1 + td; GLD(P31, a);  a = pp2 + td; GLD(P32, a);
    }
    WAITP();                         // batch 0 complete (9 = 3 batches outstanding)
    f32x4 epv0, epv1, epv2;          // exp(pot[t]) * pending-renorm, current step
#pragma unroll
    for (int r = 0; r < 4; ++r) {
        epv0[r] = __expf(P00[r]);
        epv1[r] = __expf(P01[r]);
        epv2[r] = __expf(P02[r]);
    }

    const int ksteps = ((end - t0) + 3) & ~3;    // padded steps provably inert

#define CRF_STEP(KK, LA0, LA1, LA2, NB0, NB1, NB2)                              \
    {                                                                           \
        const int t   = t0 + (KK);                                              \
        const size_t tld = (size_t)((t + 4 < Tt) ? (t + 4) : (Tt - 1)) * Nn;    \
        const float* pa_ = pp0 + tld;  GLD(LA0, pa_);                           \
        const float* pb_ = pp1 + tld;  GLD(LA1, pb_);                           \
        const float* pc_ = pp2 + tld;  GLD(LA2, pc_);                           \
        f32x4 z = {0.0f, 0.0f, 0.0f, 0.0f};                                     \
        f32x4 D0 = __builtin_amdgcn_mfma_f32_16x16x32_bf16(Wf[0][0], Bf0, z, 0, 0, 0); \
        f32x4 D1 = __builtin_amdgcn_mfma_f32_16x16x32_bf16(Wf[1][0], Bf0, z, 0, 0, 0); \
        f32x4 D2 = __builtin_amdgcn_mfma_f32_16x16x32_bf16(Wf[2][0], Bf0, z, 0, 0, 0); \
        D0 = __builtin_amdgcn_mfma_f32_16x16x32_bf16(Wf[0][1], Bf1, D0, 0, 0, 0); \
        D1 = __builtin_amdgcn_mfma_f32_16x16x32_bf16(Wf[1][1], Bf1, D1, 0, 0, 0); \
        D2 = __builtin_amdgcn_mfma_f32_16x16x32_bf16(Wf[2][1], Bf1, D2, 0, 0, 0); \
        f32x4 a0, a1, a2;                                                       \
        _Pragma("unroll")                                                       \
        for (int r = 0; r < 4; ++r) {                                           \
            a0[r] = D0[r] * epv0[r];                                            \
            a1[r] = D1[r] * epv1[r];                                            \
            a2[r] = D2[r] * epv2[r];                                            \
        }                                                                       \
        const float cb = __shfl(a0[0], slC);                                    \
        const float rr = __builtin_amdgcn_rcpf(fmaxf(cb, 1e-30f));              \
        const float lg = safe_log(cb);                                          \
        gacc += ((t >= start) && (t < end) && (t + 1 < len_ln)) ? lg : 0.0f;    \
        const bool act = (t < len_ln);                                          \
        _Pragma("unroll")                                                       \
        for (int r = 0; r < 4; ++r) {                                           \
            prev0[r] = act ? a0[r] : prev0[r];                                  \
            prev1[r] = act ? a1[r] : prev1[r];                                  \
            prev2[r] = act ? a2[r] : prev2[r];                                  \
        }                                                                       \
        pk00 = pack2(prev0[0], prev0[1]);                                       \
        pk01 = pack2(prev0[2], prev0[3]);                                       \
        pk10 = pack2(prev1[0], prev1[1]);                                       \
        pk11 = pack2(prev1[2], prev1[3]);                                       \
        pk20 = pack2(prev2[0], prev2[1]);                                       \
        pk21 = pack2(prev2[2], prev2[3]);                                       \
        Bf0 = __builtin_bit_cast(bf16x8, (u32x4){pk00, pk01, pk10, pk11});      \
        Bf1 = __builtin_bit_cast(bf16x8, (u32x4){                               \
            (unsigned int)__shfl((int)pk20, slA), (unsigned int)__shfl((int)pk21, slA), \
            (unsigned int)__shfl((int)pk20, slB), (unsigned int)__shfl((int)pk21, slB)}); \
        WAITP();                     /* batch KK+1 landed; 3 batches in flight */ \
        _Pragma("unroll")                                                       \
        for (int r = 0; r < 4; ++r) {                                           \
            epv0[r] = __expf(NB0[r]) * rr;                                      \
            epv1[r] = __expf(NB1[r]) * rr;                                      \
            epv2[r] = __expf(NB2[r]) * rr;                                      \
        }                                                                       \
    }

    for (int k = 0; k < ksteps; k += 4) {
        CRF_STEP(k + 0, P00, P01, P02, P10, P11, P12);
        CRF_STEP(k + 1, P10, P11, P12, P20, P21, P22);
        CRF_STEP(k + 2, P20, P21, P22, P30, P31, P32);
        CRF_STEP(k + 3, P30, P31, P32, P00, P01, P02);
    }
#undef CRF_STEP

    asm volatile("s_waitcnt vmcnt(0)");          // drain in-flight asm loads

    // Chunk contribution; the unique "last" chunk adds the logsumexp.
    // (final rowsum is pre-division by the last active step's c, whose log
    //  was deliberately NOT added to gacc - exact telescoping.)
    float rs = prev0[0] + prev0[1] + prev0[2] + prev0[3]
             + prev1[0] + prev1[1] + prev1[2] + prev1[3]
             + prev2[0] + prev2[1] + prev2[2] + prev2[3];
    rs += __shfl_xor(rs, 16);
    rs += __shfl_xor(rs, 32);                    // full 48-state sum per lane

    const bool active_chunk = (c == 0) || (c * Lc < len_ln);
    const bool last = active_chunk && (len_ln <= (c + 1) * Lc);
    const float G = gacc + (last ? safe_log(rs) : 0.0f);
    if (lane < 16) atomicAdd(&out[s0 + ln], G);
}

extern "C" void kernel_launch(void* const* d_in, const int* in_sizes, int n_in,
                              void* d_out, int out_size, void* d_ws, size_t ws_size,
                              hipStream_t stream)
{
    const float* pot   = (const float*)d_in[0];
    const int*   ytrue = (const int*)  d_in[1];
    const int*   lens  = (const int*)  d_in[2];
    const float* trans = (const float*)d_in[3];
    float*       out   = (float*)d_out;

    hipMemsetAsync(out, 0, (size_t)out_size * sizeof(float), stream);
    crf_fused<<<dim3(NG * Cc), dim3(64), 0, stream>>>(pot, ytrue, lens, trans, out);
}

// Round 6
// 185.836 us; speedup vs baseline: 1.0137x; 1.0137x over previous
//
#include <hip/hip_runtime.h>
#include <cstdint>
#include <cstddef>

// Problem constants (from reference: B,T,N = 512,1024,48)
constexpr int Bb = 512;
constexpr int Tt = 1024;
constexpr int Nn = 48;
constexpr int SG = 16;          // sequences per wave (MFMA N dimension here)
constexpr int NG = Bb / SG;     // 32 sequence-groups
constexpr int Cc = 64;          // time-chunks per sequence (grid = 2048 -> 2 waves/SIMD)
constexpr int Lc = Tt / Cc;     // 16 steps per chunk window
constexpr int Wb = 32;          // burn-in steps (validated in earlier session)
constexpr int TILE = 3328;      // 16 rows x 13 granules x 16 B (granule 12 of each row = pad)

typedef short bf16x8 __attribute__((ext_vector_type(8)));
typedef float f32x4  __attribute__((ext_vector_type(4)));
typedef unsigned int u32x4 __attribute__((ext_vector_type(4)));

__device__ __forceinline__ unsigned int bf16_rne(float x) {
    const unsigned int u = __float_as_uint(x);
    return ((u + 0x7FFFu + ((u >> 16) & 1u)) >> 16);
}
__device__ __forceinline__ unsigned int pack2(float lo, float hi) {
    return bf16_rne(lo) | (bf16_rne(hi) << 16);
}
__device__ __forceinline__ float safe_log(float x) {
    return __logf(fmaxf(x, 1e-30f));   // NaN/inf-proof (fmax discards NaN)
}
// Async global->LDS, 16 B per lane. Dest = wave-uniform base + lane*16 (HW rule);
// source address is per-lane, which is how we realize the padded LDS layout.
__device__ __forceinline__ void gll16(const float* g, const char* l) {
    __builtin_amdgcn_global_load_lds(
        (const __attribute__((address_space(1))) void*)g,
        (__attribute__((address_space(3))) void*)l, 16, 0, 0);
}

// ---------------------------------------------------------------------------
// R6: prefetch lives in LDS, not VGPRs. R4/R5 proved the register-pinned asm
// pipeline is unsound under regalloc (spilled asm outputs are stored without
// vmcnt waits -> absmax 4/96). global_load_lds holds in-flight pot data in
// LDS at zero register cost; all register values are compiler-managed again.
//
// Tile(t) = 16 seqs x 48 floats, LDS layout row-major with 13-granule row
// stride (208 B): granule (s,c) at offset (s*13+c)*16, c in [0,12), col 12 a
// written-but-never-read pad (avoids the 8-way ds_read bank conflict of a
// 192 B stride; 208 B gives the stride-1 baseline pattern). Ring of 4 slots,
// group-of-2 schedule: per boundary, one vmcnt(0) (tiles were issued one
// full group = 2 steps earlier) then issue the next group's 8 loads.
// vmcnt(0)-only discipline is immune to conservative waitcnt insertion.
//
// Step math = R3 (verified): operand-swapped MFMA, alpha as B operand,
// K-slot bijection identical on A and B; per-lane renorm with deferred
// division (epv = exp(pot)*rr_prev at step start; same values/order as R3).
// ---------------------------------------------------------------------------
__launch_bounds__(64)
__global__ void crf_fused(const float* __restrict__ pot,
                          const int*   __restrict__ ytrue,
                          const int*   __restrict__ lengths,
                          const float* __restrict__ trans,
                          float*       __restrict__ out)
{
    // 13312 B: trans (9216 B) during setup, then the 4-slot pot ring.
    __shared__ __align__(16) char smem_c[4 * TILE];
    float* trans_lds = (float*)smem_c;

    const int lane = threadIdx.x;
    const int ln   = lane & 15;          // sequence index within group (MFMA N)
    const int q    = lane >> 4;          // quad
    const int gidx = blockIdx.x >> 6;    // sequence group (Cc == 64)
    const int c    = blockIdx.x & 63;    // chunk
    const int s0   = gidx * SG;

    for (int i = lane; i < Nn * Nn; i += 64) trans_lds[i] = trans[i];
    __syncthreads();

    // ---- Gold-path score: sequence b = blockIdx.x>>2, quarter h = blockIdx.x&3.
    {
        const int    b    = blockIdx.x >> 2;
        const int    h    = blockIdx.x & 3;
        const int    lenb = lengths[b];
        const int*   yrow = ytrue + (size_t)b * Tt;
        const float* prow = pot + (size_t)b * Tt * Nn;
        float gold = 0.0f;
#pragma unroll
        for (int k = 0; k < Tt / 256; ++k) {          // 4 iters x 64 lanes = 256 t
            const int   t    = h * (Tt / 4) + lane + 64 * k;
            const int   yt   = yrow[t];
            const int   ytm1 = yrow[(t > 0) ? (t - 1) : 0];
            const float u    = prow[(size_t)t * Nn + yt];
            const float tr   = trans_lds[ytm1 * Nn + yt];
            gold += (t < lenb) ? u : 0.0f;
            gold += (t >= 1 && t < lenb) ? tr : 0.0f;
        }
#pragma unroll
        for (int off = 32; off > 0; off >>= 1) gold += __shfl_xor(gold, off);
        if (lane == 0) atomicAdd(&out[b], -gold);
    }

    const int len_ln = lengths[s0 + ln];         // per-lane sequence length
    int lmax = len_ln;
#pragma unroll
    for (int off = 8; off > 0; off >>= 1) {
        const int o = __shfl_xor(lmax, off);
        lmax = (o > lmax) ? o : lmax;
    }

    const int start = (c == 0) ? 1 : c * Lc;
    if (c > 0 && start >= lmax) return;          // uniform exit (gold already done)
    const int end = ((c + 1) * Lc < lmax) ? (c + 1) * Lc : lmax;

    // A-operand fragments (E^T slices). K-slot->state bijection (same on B):
    //   kc0: slot (q,d) -> 16*(d>>2)+4q+(d&3)  => B0 = lane's own packed pk words.
    //   kc1: slot (q,d) -> 32+8q+d (q<2)       => B1 = 4 bpermute pulls of pk2x.
    bf16x8 Wf[3][2];
#pragma unroll
    for (int nt = 0; nt < 3; ++nt)
#pragma unroll
        for (int kc = 0; kc < 2; ++kc)
#pragma unroll
            for (int d = 0; d < 8; ++d) {
                int i;
                if (kc == 0) {
                    i = 16 * (d >> 2) + 4 * q + (d & 3);
                } else {
                    i = (q < 2) ? (32 + 8 * q + d) : -1;
                }
                const float v = (i >= 0) ? __expf(trans_lds[i * Nn + nt * 16 + ln]) : 0.0f;
                Wf[nt][kc][d] = (short)bf16_rne(v);
            }

    // Cross-lane source lanes for B1 words / c broadcast.
    const int slA = ((2 * q) & 3) * 16 + ln;     // quad 2q   (meaningful for q<2)
    const int slB = slA + 16;                    // quad 2q+1
    const int slC = ln;                          // state-0 holder for seq ln

    // Per-lane pot row pointers (init only).
    const float* prow = pot + (size_t)(s0 + ln) * (Tt * Nn);
    const float* pp0 = prow + 0 * 16 + q * 4;
    const float* pp1 = prow + 1 * 16 + q * 4;
    const float* pp2 = prow + 2 * 16 + q * 4;

    int t0 = (c == 0) ? 1 : (start - Wb);
    if (t0 < 1) t0 = 1;                          // c=1,2: exact full recompute

    // ---- Init alpha from pot[t0-1], normalized so alpha[m][0] = 1.
    f32x4 pin0 = *(const f32x4*)(pp0 + (size_t)(t0 - 1) * Nn);
    f32x4 pin1 = *(const f32x4*)(pp1 + (size_t)(t0 - 1) * Nn);
    f32x4 pin2 = *(const f32x4*)(pp2 + (size_t)(t0 - 1) * Nn);
    const float cb0 = __shfl(pin0[0], slC);

    float gacc = (c == 0) ? cb0 : 0.0f;          // per-lane (seq = ln)
    f32x4 prev0, prev1, prev2;
#pragma unroll
    for (int r = 0; r < 4; ++r) {
        prev0[r] = __expf(pin0[r] - cb0);
        prev1[r] = __expf(pin1[r] - cb0);
        prev2[r] = __expf(pin2[r] - cb0);
    }

    unsigned int pk00 = pack2(prev0[0], prev0[1]);
    unsigned int pk01 = pack2(prev0[2], prev0[3]);
    unsigned int pk10 = pack2(prev1[0], prev1[1]);
    unsigned int pk11 = pack2(prev1[2], prev1[3]);
    unsigned int pk20 = pack2(prev2[0], prev2[1]);
    unsigned int pk21 = pack2(prev2[2], prev2[3]);
    bf16x8 Bf0 = __builtin_bit_cast(bf16x8, (u32x4){pk00, pk01, pk10, pk11});
    bf16x8 Bf1 = __builtin_bit_cast(bf16x8, (u32x4){
        (unsigned int)__shfl((int)pk20, slA), (unsigned int)__shfl((int)pk21, slA),
        (unsigned int)__shfl((int)pk20, slB), (unsigned int)__shfl((int)pk21, slB)});

    // ---- Staging granule map: instruction i, lane l -> granule g = 64i+l;
    // row s = g/13, chunk cgr = min(g%13, 11) (col 12 pad = dup of col 11).
    // LDS dest is linear (g*16); the padded layout comes from this source map.
    const float* srcp[4];
#pragma unroll
    for (int i = 0; i < 4; ++i) {
        int g = 64 * i + lane;
        int s = g / 13;  if (s > 15) s = 15;
        int cg = g % 13; if (cg > 11) cg = 11;
        srcp[i] = pot + (size_t)(s0 + s) * (Tt * Nn) + 4 * cg;
    }

    __syncthreads();   // retire all trans_lds reads before the ring overwrites it

#define STAGE(tt, SLOT) do {                                                    \
        const size_t toff_ = (size_t)(((tt) < Tt) ? (tt) : (Tt - 1)) * Nn;      \
        char* lb_ = smem_c + (SLOT) * TILE;                                     \
        gll16(srcp[0] + toff_, lb_);                                            \
        gll16(srcp[1] + toff_, lb_ + 1024);                                     \
        gll16(srcp[2] + toff_, lb_ + 2048);                                     \
        if (lane < 16) gll16(srcp[3] + toff_, lb_ + 3072);                      \
    } while (0)

// Boundary before steps {KK, KK+1}: their tiles were issued one group (2
// steps) earlier -> vmcnt(0) is cheap; then issue tiles {KK+2, KK+3} whose
// slots hold already-consumed data. "memory" clobber orders the C-level
// ds_reads of the steps after the wait.
#define BOUNDARY(KK) do {                                                       \
        asm volatile("s_waitcnt vmcnt(0)" ::: "memory");                        \
        STAGE(t0 + (KK) + 2, ((KK) + 2) & 3);                                   \
        STAGE(t0 + (KK) + 3, ((KK) + 3) & 3);                                   \
    } while (0)

    const int lnq13 = ln * 13 + q;               // granule index of (seq ln, chunk q)
    float rrp = 1.0f;                            // deferred renorm carried between steps

    // Prologue: issue tiles t0, t0+1 into slots 0,1.
    STAGE(t0 + 0, 0);
    STAGE(t0 + 1, 1);

    const int ksteps = ((end - t0) + 3) & ~3;    // padded steps provably inert

#define CRF_STEP(KK, SLOT)                                                      \
    {                                                                           \
        const int t_ = t0 + (KK);                                               \
        const f32x4* tp_ = (const f32x4*)(smem_c + (SLOT) * TILE);              \
        const f32x4 PA_ = tp_[lnq13];                                           \
        const f32x4 PB_ = tp_[lnq13 + 4];                                       \
        const f32x4 PC_ = tp_[lnq13 + 8];                                       \
        f32x4 z_ = {0.0f, 0.0f, 0.0f, 0.0f};                                    \
        f32x4 D0_ = __builtin_amdgcn_mfma_f32_16x16x32_bf16(Wf[0][0], Bf0, z_, 0, 0, 0); \
        f32x4 D1_ = __builtin_amdgcn_mfma_f32_16x16x32_bf16(Wf[1][0], Bf0, z_, 0, 0, 0); \
        f32x4 D2_ = __builtin_amdgcn_mfma_f32_16x16x32_bf16(Wf[2][0], Bf0, z_, 0, 0, 0); \
        D0_ = __builtin_amdgcn_mfma_f32_16x16x32_bf16(Wf[0][1], Bf1, D0_, 0, 0, 0); \
        D1_ = __builtin_amdgcn_mfma_f32_16x16x32_bf16(Wf[1][1], Bf1, D1_, 0, 0, 0); \
        D2_ = __builtin_amdgcn_mfma_f32_16x16x32_bf16(Wf[2][1], Bf1, D2_, 0, 0, 0); \
        f32x4 a0_, a1_, a2_;                                                    \
        _Pragma("unroll")                                                       \
        for (int r = 0; r < 4; ++r) {                                           \
            a0_[r] = D0_[r] * (__expf(PA_[r]) * rrp);                           \
            a1_[r] = D1_[r] * (__expf(PB_[r]) * rrp);                           \
            a2_[r] = D2_[r] * (__expf(PC_[r]) * rrp);                           \
        }                                                                       \
        const float cb_ = __shfl(a0_[0], slC);                                  \
        const float rr_ = __builtin_amdgcn_rcpf(fmaxf(cb_, 1e-30f));            \
        const float lg_ = safe_log(cb_);                                        \
        gacc += ((t_ >= start) && (t_ < end) && (t_ + 1 < len_ln)) ? lg_ : 0.0f; \
        const bool act_ = (t_ < len_ln);                                        \
        _Pragma("unroll")                                                       \
        for (int r = 0; r < 4; ++r) {                                           \
            prev0[r] = act_ ? a0_[r] : prev0[r];                                \
            prev1[r] = act_ ? a1_[r] : prev1[r];                                \
            prev2[r] = act_ ? a2_[r] : prev2[r];                                \
        }                                                                       \
        pk00 = pack2(prev0[0], prev0[1]);                                       \
        pk01 = pack2(prev0[2], prev0[3]);                                       \
        pk10 = pack2(prev1[0], prev1[1]);                                       \
        pk11 = pack2(prev1[2], prev1[3]);                                       \
        pk20 = pack2(prev2[0], prev2[1]);                                       \
        pk21 = pack2(prev2[2], prev2[3]);                                       \
        Bf0 = __builtin_bit_cast(bf16x8, (u32x4){pk00, pk01, pk10, pk11});      \
        Bf1 = __builtin_bit_cast(bf16x8, (u32x4){                               \
            (unsigned int)__shfl((int)pk20, slA), (unsigned int)__shfl((int)pk21, slA), \
            (unsigned int)__shfl((int)pk20, slB), (unsigned int)__shfl((int)pk21, slB)}); \
        rrp = rr_;                                                              \
    }

    for (int k = 0; k < ksteps; k += 4) {
        BOUNDARY(k);
        CRF_STEP(k + 0, 0);
        CRF_STEP(k + 1, 1);
        BOUNDARY(k + 2);
        CRF_STEP(k + 2, 2);
        CRF_STEP(k + 3, 3);
    }
#undef CRF_STEP
#undef BOUNDARY
#undef STAGE

    asm volatile("s_waitcnt vmcnt(0)" ::: "memory");   // drain trailing staging

    // Chunk contribution; the unique "last" chunk adds the logsumexp.
    // (final rowsum is pre-division by the last active step's c, whose log
    //  was deliberately NOT added to gacc - exact telescoping.)
    float rs = prev0[0] + prev0[1] + prev0[2] + prev0[3]
             + prev1[0] + prev1[1] + prev1[2] + prev1[3]
             + prev2[0] + prev2[1] + prev2[2] + prev2[3];
    rs += __shfl_xor(rs, 16);
    rs += __shfl_xor(rs, 32);                    // full 48-state sum per lane

    const bool active_chunk = (c == 0) || (c * Lc < len_ln);
    const bool last = active_chunk && (len_ln <= (c + 1) * Lc);
    const float G = gacc + (last ? safe_log(rs) : 0.0f);
    if (lane < 16) atomicAdd(&out[s0 + ln], G);
}

extern "C" void kernel_launch(void* const* d_in, const int* in_sizes, int n_in,
                              void* d_out, int out_size, void* d_ws, size_t ws_size,
                              hipStream_t stream)
{
    const float* pot   = (const float*)d_in[0];
    const int*   ytrue = (const int*)  d_in[1];
    const int*   lens  = (const int*)  d_in[2];
    const float* trans = (const float*)d_in[3];
    float*       out   = (float*)d_out;

    hipMemsetAsync(out, 0, (size_t)out_size * sizeof(float), stream);
    crf_fused<<<dim3(NG * Cc), dim3(64), 0, stream>>>(pot, ytrue, lens, trans, out);
}